// Round 6
// baseline (2725.744 us; speedup 1.0000x reference)
//
#include <hip/hip_runtime.h>

constexpr int kNodes = 1000000;
constexpr int kEdges = 32000000;

// ---------------- Direct-atomic path (XCD-replicated accumulators) --------
// The R0-R5 sort pipeline (tile counting-sort -> record arena -> bucket
// accum) plateaued at ~700 us: its orcq gathers alone are ~250K scattered
// vmem lane-ops/CU, and the 280 MB record array is written AND re-read just
// to convert scatter-atomics into streaming. Here we do the scatter
// directly: one u32 atomic per (edge,endpoint) = 64M atomics, spread over
// 8 replica accumulators (4 MB each, L2-resident). Replica = blockIdx&7,
// matching the default round-robin workgroup->XCD dispatch, so each
// replica's lines live in one XCD's L2 (locality only -- correctness never
// depends on the mapping; the merge sums all replicas).
// Replica cell = deg<<24 | sum(q16):  deg <= ~110 max (Poisson 64 over 1M
// nodes) < 255; sum <= 110*65535 = 7.2M < 2^24. Exact in integer arithmetic.
constexpr int kReps = 8;

constexpr size_t kAccBytes  = (size_t)kReps * kNodes * 4;   // 32 MB
constexpr size_t kOrcqOff   = kAccBytes;
constexpr size_t kOrcqBytes = (size_t)kNodes * 2;           // 2 MB
constexpr size_t kWsNeeded  = kOrcqOff + kOrcqBytes;        // 34 MB

__global__ __launch_bounds__(256) void quant_orc(
        const float* __restrict__ orc, unsigned short* __restrict__ orcq) {
    const int i = (blockIdx.x * 256 + threadIdx.x) * 4;
    if (i >= kNodes) return;
    const float4 v = *reinterpret_cast<const float4*>(orc + i);
    unsigned q0 = __float2uint_rn((v.x + 1.0f) * 32768.0f);
    unsigned q1 = __float2uint_rn((v.y + 1.0f) * 32768.0f);
    unsigned q2 = __float2uint_rn((v.z + 1.0f) * 32768.0f);
    unsigned q3 = __float2uint_rn((v.w + 1.0f) * 32768.0f);
    q0 = q0 > 65535u ? 65535u : q0;
    q1 = q1 > 65535u ? 65535u : q1;
    q2 = q2 > 65535u ? 65535u : q2;
    q3 = q3 > 65535u ? 65535u : q3;
    ushort4 q;
    q.x = (unsigned short)q0; q.y = (unsigned short)q1;
    q.z = (unsigned short)q2; q.w = (unsigned short)q3;
    *reinterpret_cast<ushort4*>(orcq + i) = q;
}

__global__ __launch_bounds__(256) void zero_rep(unsigned* __restrict__ acc) {
    const int i = blockIdx.x * 256 + threadIdx.x;     // 2M uint4 = 8M u32
    if (i < kReps * kNodes / 4) {
        uint4 z; z.x = z.y = z.z = z.w = 0u;
        reinterpret_cast<uint4*>(acc)[i] = z;
    }
}

// 8 edges per thread: 4 coalesced int4 loads, 16 L2-resident orcq gathers
// (all independent -> deep outstanding-miss queue), 16 u32 atomics into the
// block's XCD-local replica.
__global__ __launch_bounds__(256) void edge_direct(
        const int* __restrict__ ei, const unsigned short* __restrict__ orcq,
        unsigned* __restrict__ acc) {
    const int e0 = blockIdx.x * 2048 + threadIdx.x * 8;
    unsigned* __restrict__ rep = acc + (size_t)(blockIdx.x & (kReps - 1)) * kNodes;
    const int4 sa = *reinterpret_cast<const int4*>(ei + e0);
    const int4 sb = *reinterpret_cast<const int4*>(ei + e0 + 4);
    const int4 da = *reinterpret_cast<const int4*>(ei + kEdges + e0);
    const int4 db = *reinterpret_cast<const int4*>(ei + kEdges + e0 + 4);
    int s[8], d[8];
    s[0] = sa.x; s[1] = sa.y; s[2] = sa.z; s[3] = sa.w;
    s[4] = sb.x; s[5] = sb.y; s[6] = sb.z; s[7] = sb.w;
    d[0] = da.x; d[1] = da.y; d[2] = da.z; d[3] = da.w;
    d[4] = db.x; d[5] = db.y; d[6] = db.z; d[7] = db.w;
    unsigned qs[8], qd[8];
    #pragma unroll
    for (int j = 0; j < 8; ++j) {
        qs[j] = orcq[d[j]];        // q(orc[d]) -> contribution to s
        qd[j] = orcq[s[j]];        // q(orc[s]) -> contribution to d
    }
    #pragma unroll
    for (int j = 0; j < 8; ++j) {
        atomicAdd(&rep[s[j]], qs[j] | 0x1000000u);
        atomicAdd(&rep[d[j]], qd[j] | 0x1000000u);
    }
}

// ---------------- Fallback (atomic u64) path ----------------
constexpr float kScale = 1048576.0f;           // 2^20
constexpr float kInvScale = 1.0f / 1048576.0f;
constexpr long long kBias = 1ll << 36;

__global__ __launch_bounds__(256) void zero_acc(unsigned long long* __restrict__ acc) {
    int i = blockIdx.x * 256 + threadIdx.x;
    if (i < kNodes) acc[i] = 0ull;
}

__global__ __launch_bounds__(256) void edge_kernel(
        const int* __restrict__ ei,
        const float* __restrict__ orc,
        unsigned long long* __restrict__ acc) {
    int t = blockIdx.x * 256 + threadIdx.x;
    int e0 = t * 4;
    if (e0 >= kEdges) return;
    const int4 s4 = *reinterpret_cast<const int4*>(ei + e0);
    const int4 d4 = *reinterpret_cast<const int4*>(ei + kEdges + e0);
    const int ss[4] = {s4.x, s4.y, s4.z, s4.w};
    const int dd[4] = {d4.x, d4.y, d4.z, d4.w};
    #pragma unroll
    for (int k = 0; k < 4; ++k) {
        const float os = orc[ss[k]];
        const float od = orc[dd[k]];
        const unsigned long long ps =
            (1ull << 48) + (unsigned long long)(kBias + (long long)__float2ll_rn(od * kScale));
        const unsigned long long pd =
            (1ull << 48) + (unsigned long long)(kBias + (long long)__float2ll_rn(os * kScale));
        atomicAdd(&acc[ss[k]], ps);
        atomicAdd(&acc[dd[k]], pd);
    }
}

// ---------------- Node phase ----------------
// MODE 0: u64 cell, deg<<48 | biased 2^20 fixed sum.
// MODE 4: kReps u32 replicas, each deg<<24 | sum(q16); merge then average.
template <int MODE>
__global__ __launch_bounds__(256) void node_kernel(
        const float* __restrict__ orc,
        const unsigned long long* __restrict__ acc64,
        const unsigned* __restrict__ acc32,
        const float* __restrict__ W1, const float* __restrict__ b1,
        const float* __restrict__ W2, const float* __restrict__ b2,
        const float* __restrict__ gamma, const float* __restrict__ beta,
        float* __restrict__ out) {
    const int i = blockIdx.x * 256 + threadIdx.x;
    if (i >= kNodes) return;

    const float x0 = orc[i];
    float nb;
    if (MODE == 0) {
        const unsigned long long p = acc64[i];
        const unsigned deg = (unsigned)(p >> 48);
        const long long sf = (long long)(p & ((1ull << 48) - 1)) - (long long)deg * kBias;
        const float s = (float)sf * kInvScale;
        nb = (deg > 0) ? s / (float)deg : 0.0f;
    } else {
        unsigned deg = 0u, sumq = 0u;
        #pragma unroll
        for (int r = 0; r < kReps; ++r) {
            const unsigned p = acc32[(size_t)r * kNodes + i];
            deg += p >> 24;
            sumq += p & 0xFFFFFFu;
        }
        nb = (deg > 0)
            ? ((float)sumq * (1.0f / 32768.0f) / (float)deg - 1.0f) : 0.0f;
    }

    constexpr float kPi = 3.14159265358979323846f;
    float Phi[16];
    const float n0 = __saturatef((x0 + 1.0f) * 0.5f);
    const float n1 = __saturatef((nb + 1.0f) * 0.5f);
    #pragma unroll
    for (int k = 0; k < 4; ++k) {
        const float a0 = n0 * (float)(k + 1) * kPi;
        const float a1 = n1 * (float)(k + 1) * kPi;
        Phi[2 * k]     = __sinf(a0);
        Phi[2 * k + 1] = __cosf(a0);
        Phi[8 + 2 * k]     = __sinf(a1);
        Phi[8 + 2 * k + 1] = __cosf(a1);
    }

    float y[16];
    #pragma unroll
    for (int d = 0; d < 16; ++d) y[d] = b2[d];
    #pragma unroll
    for (int j = 0; j < 32; ++j) {
        float a = b1[j];
        #pragma unroll
        for (int d = 0; d < 16; ++d) a = fmaf(Phi[d], W1[j * 16 + d], a);
        a = fmaxf(a, 0.0f);
        #pragma unroll
        for (int d = 0; d < 16; ++d) y[d] = fmaf(a, W2[d * 32 + j], y[d]);
    }

    float mu = 0.0f;
    #pragma unroll
    for (int d = 0; d < 16; ++d) mu += y[d];
    mu *= (1.0f / 16.0f);
    float var = 0.0f;
    #pragma unroll
    for (int d = 0; d < 16; ++d) { const float t = y[d] - mu; var = fmaf(t, t, var); }
    var *= (1.0f / 16.0f);
    const float inv = rsqrtf(var + 1e-5f);

    float4* o4 = reinterpret_cast<float4*>(out + (size_t)i * 16);
    #pragma unroll
    for (int q = 0; q < 4; ++q) {
        float4 o;
        o.x = (y[4 * q + 0] - mu) * inv * gamma[4 * q + 0] + beta[4 * q + 0] + Phi[4 * q + 0];
        o.y = (y[4 * q + 1] - mu) * inv * gamma[4 * q + 1] + beta[4 * q + 1] + Phi[4 * q + 1];
        o.z = (y[4 * q + 2] - mu) * inv * gamma[4 * q + 2] + beta[4 * q + 2] + Phi[4 * q + 2];
        o.w = (y[4 * q + 3] - mu) * inv * gamma[4 * q + 3] + beta[4 * q + 3] + Phi[4 * q + 3];
        o4[q] = o;
    }
}

extern "C" void kernel_launch(void* const* d_in, const int* in_sizes, int n_in,
                              void* d_out, int out_size, void* d_ws, size_t ws_size,
                              hipStream_t stream) {
    const float* orc   = (const float*)d_in[0];
    const int*   ei    = (const int*)d_in[1];
    const float* W1    = (const float*)d_in[2];
    const float* b1    = (const float*)d_in[3];
    const float* W2    = (const float*)d_in[4];
    const float* b2    = (const float*)d_in[5];
    const float* gamma = (const float*)d_in[6];
    const float* beta  = (const float*)d_in[7];
    float* out = (float*)d_out;
    char* ws = (char*)d_ws;

    if (ws_size >= kWsNeeded) {
        unsigned* acc = (unsigned*)ws;
        unsigned short* orcq = (unsigned short*)(ws + kOrcqOff);
        quant_orc<<<(kNodes / 4 + 255) / 256, 256, 0, stream>>>(orc, orcq);
        zero_rep<<<(kReps * kNodes / 4 + 255) / 256, 256, 0, stream>>>(acc);
        edge_direct<<<kEdges / 2048, 256, 0, stream>>>(ei, orcq, acc);
        node_kernel<4><<<(kNodes + 255) / 256, 256, 0, stream>>>(
            orc, nullptr, acc, W1, b1, W2, b2, gamma, beta, out);
    } else {
        unsigned long long* acc = (unsigned long long*)ws;  // 8 MB
        zero_acc<<<(kNodes + 255) / 256, 256, 0, stream>>>(acc);
        edge_kernel<<<(kEdges / 4 + 255) / 256, 256, 0, stream>>>(ei, orc, acc);
        node_kernel<0><<<(kNodes + 255) / 256, 256, 0, stream>>>(
            orc, acc, nullptr, W1, b1, W2, b2, gamma, beta, out);
    }
}

// Round 8
// 819.240 us; speedup vs baseline: 3.3272x; 3.3272x over previous
//
#include <hip/hip_runtime.h>

constexpr int kNodes = 1000000;
constexpr int kEdges = 32000000;

// ---------------- Tile-sorted scatter path (slab + arena, 2-tile pipe) ----
// 256 buckets x 4096 nodes. Record u32 = (node&4095)<<16 | q16,
// q16 = clamp(round((orc_other+1)*32768), 0, 65535)  (error <= 1.5e-5).
// Producer: each block processes TWO 4096-edge tiles; edges + all orcq
// gathers for both tiles are issued up front, so tile-B's gather latency
// (the critical chain) hides under tile-A's rank/alloc/flush. Per tile:
// rank atomic r=atomicAdd(cnt[b]) places the record at slab[b*64+r]
// (no histogram pass). P(count>64) ~ 1e-8 per segment -> ~0.02 expected
// overflows total, routed exactly via a global overflow list + fixup.
// Arena: per-bucket atomicAdd(gcur[b], paddedcount) gives each tile a
// 16B-aligned contiguous run in that bucket's region; flush = int4 stores.
// Consumer: one block-pair per bucket streams the dense arena region with
// paired uint4 loads into dual LDS accumulator copies.
// R6 calibration: direct global atomics = 2.4 ms for 64M (memory-side,
// ~28 G/s) -- the sort pipeline is mandatory.
constexpr int NB = 256;
constexpr int BSHIFT = 12;
constexpr int BNODES = 4096;
constexpr int NBUSED = (kNodes + BNODES - 1) / BNODES;   // 245
constexpr int EPT = 4096;                 // edges per tile
constexpr int TILES = (kEdges + EPT - 1) / EPT;          // 7813
constexpr int SLOT = 64;                  // LDS slab slots per bucket (pow2)
constexpr int GP = SLOT / 4;              // int4 groups per slab (16, pow2)
constexpr int CAP = 284672;               // per-bucket arena capacity (mult 4)
                                          // padded mean ~272.7K, 23 sigma
constexpr int SPLIT = 2;
constexpr unsigned PADREC = 0x10000000u;  // local node 4096 -> LDS sink slot
constexpr unsigned OVFCAP = 8192;

constexpr size_t kArenaBytes = (size_t)NBUSED * CAP * 4;   // ~279 MB
constexpr size_t kCurOff    = kArenaBytes;
constexpr size_t kCurBytes  = (size_t)NB * 64 + 64;        // strided cursors + ovfcnt
constexpr size_t kAccOff    = kCurOff + kCurBytes;
constexpr size_t kAccBytes  = (size_t)SPLIT * kNodes * 4;  // 8 MB
constexpr size_t kOrcqOff   = kAccOff + kAccBytes;
constexpr size_t kOrcqBytes = (size_t)kNodes * 2;          // 2 MB
constexpr size_t kOvfOff    = (kOrcqOff + kOrcqBytes + 7) & ~(size_t)7;
constexpr size_t kOvfBytes  = (size_t)OVFCAP * 8;          // 64 KB
constexpr size_t kWsNeeded  = kOvfOff + kOvfBytes;         // ~289 MB

__global__ __launch_bounds__(256) void quant_orc(
        const float* __restrict__ orc, unsigned short* __restrict__ orcq,
        unsigned* __restrict__ gcur) {
    if (blockIdx.x == 0) {
        if (threadIdx.x < NB) gcur[threadIdx.x * 16] = 0u;
        if (threadIdx.x == 0) gcur[NB * 16] = 0u;       // overflow counter
    }
    const int i = (blockIdx.x * 256 + threadIdx.x) * 4;
    if (i >= kNodes) return;
    const float4 v = *reinterpret_cast<const float4*>(orc + i);
    unsigned q0 = __float2uint_rn((v.x + 1.0f) * 32768.0f);
    unsigned q1 = __float2uint_rn((v.y + 1.0f) * 32768.0f);
    unsigned q2 = __float2uint_rn((v.z + 1.0f) * 32768.0f);
    unsigned q3 = __float2uint_rn((v.w + 1.0f) * 32768.0f);
    q0 = q0 > 65535u ? 65535u : q0;
    q1 = q1 > 65535u ? 65535u : q1;
    q2 = q2 > 65535u ? 65535u : q2;
    q3 = q3 > 65535u ? 65535u : q3;
    ushort4 q;
    q.x = (unsigned short)q0; q.y = (unsigned short)q1;
    q.z = (unsigned short)q2; q.w = (unsigned short)q3;
    *reinterpret_cast<ushort4*>(orcq + i) = q;
}

__global__ __launch_bounds__(1024, 8) void scatter_sort(
        const int* __restrict__ ei, const unsigned short* __restrict__ orcq,
        unsigned* __restrict__ arena, unsigned* __restrict__ gcur,
        unsigned long long* __restrict__ ovf) {
    __shared__ alignas(16) unsigned slab[NB * SLOT];   // 64 KB
    __shared__ unsigned cntA[NB], cntB[NB];            // per-tile rank cursors
    __shared__ unsigned pcs[NB];                       // padded counts
    __shared__ unsigned dstadd[NB];                    // arena dst base
    const int tid = threadIdx.x;
    const int tA = blockIdx.x * 2;
    const int tB = tA + 1;
    const int k4 = tid * 4;

    // preload BOTH tiles: edges + orcq gathers. Tile-B's gather latency
    // (the critical chain) drains under tile-A's full processing.
    const int neA = min(EPT, kEdges - tA * EPT);
    const bool actA = k4 < neA;
    int4 sA, dA; sA.x = sA.y = sA.z = sA.w = 0; dA = sA;
    unsigned pA0 = 0, pA1 = 0, pA2 = 0, pA3 = 0;
    if (actA) {
        sA = *reinterpret_cast<const int4*>(ei + tA * EPT + k4);
        dA = *reinterpret_cast<const int4*>(ei + kEdges + tA * EPT + k4);
        const unsigned a0 = orcq[dA.x], a1 = orcq[dA.y],
                       a2 = orcq[dA.z], a3 = orcq[dA.w];
        const unsigned b0 = orcq[sA.x], b1 = orcq[sA.y],
                       b2 = orcq[sA.z], b3 = orcq[sA.w];
        pA0 = a0 | (b0 << 16); pA1 = a1 | (b1 << 16);
        pA2 = a2 | (b2 << 16); pA3 = a3 | (b3 << 16);
    }
    const int neB = (tB < TILES) ? min(EPT, kEdges - tB * EPT) : 0;
    const bool actB = k4 < neB;
    int4 sB, dB; sB.x = sB.y = sB.z = sB.w = 0; dB = sB;
    unsigned pB0 = 0, pB1 = 0, pB2 = 0, pB3 = 0;
    if (actB) {
        sB = *reinterpret_cast<const int4*>(ei + tB * EPT + k4);
        dB = *reinterpret_cast<const int4*>(ei + kEdges + tB * EPT + k4);
        const unsigned a0 = orcq[dB.x], a1 = orcq[dB.y],
                       a2 = orcq[dB.z], a3 = orcq[dB.w];
        const unsigned b0 = orcq[sB.x], b1 = orcq[sB.y],
                       b2 = orcq[sB.z], b3 = orcq[sB.w];
        pB0 = a0 | (b0 << 16); pB1 = a1 | (b1 << 16);
        pB2 = a2 | (b2 << 16); pB3 = a3 | (b3 << 16);
    }

    if (tid < NB) { cntA[tid] = 0u; cntB[tid] = 0u; }
    __syncthreads();

    // one record: rank into CNT, store to slab (or overflow list)
    #define RANK1(CNT, N, Q) { \
        const unsigned b_ = (unsigned)(N) >> BSHIFT; \
        const unsigned r_ = atomicAdd(&CNT[b_], 1u); \
        if (r_ < (unsigned)SLOT) { \
            slab[(b_ << 6) + r_] = (((unsigned)(N) & (BNODES - 1)) << 16) | (Q); \
        } else { \
            const unsigned oi_ = atomicAdd(&gcur[NB * 16], 1u); \
            if (oi_ < OVFCAP) \
                ovf[oi_] = ((unsigned long long)(unsigned)(N) << 16) | (Q); \
        } }

    // per-bucket arena allocation + tail pad (tid<NB lanes only)
    #define ALLOC(CNT) { \
        unsigned c_ = CNT[tid]; \
        c_ = c_ > (unsigned)SLOT ? (unsigned)SLOT : c_; \
        const unsigned pc_ = (c_ + 3u) & ~3u; \
        pcs[tid] = pc_; \
        unsigned g_ = atomicAdd(&gcur[tid * 16], pc_); \
        if (g_ + pc_ > (unsigned)CAP) g_ = CAP - pc_; \
        dstadd[tid] = (unsigned)tid * CAP + g_; \
        for (unsigned j_ = c_; j_ < pc_; ++j_) slab[(tid << 6) + j_] = PADREC; }

    // int4 flush of live groups (NB*GP = 4096 -> exactly 4 iters/thread)
    #define FLUSH { \
        for (int k_ = tid; k_ < NB * GP; k_ += 1024) { \
            const int b_ = k_ >> 4; \
            const int g4_ = (k_ & 15) << 2; \
            if ((unsigned)g4_ < pcs[b_]) \
                *reinterpret_cast<int4*>(arena + dstadd[b_] + g4_) = \
                    *reinterpret_cast<const int4*>(slab + (b_ << 6) + g4_); \
        } }

    // ---- tile A ----
    if (actA) {
        RANK1(cntA, sA.x, pA0 & 0xFFFFu) RANK1(cntA, sA.y, pA1 & 0xFFFFu)
        RANK1(cntA, sA.z, pA2 & 0xFFFFu) RANK1(cntA, sA.w, pA3 & 0xFFFFu)
        RANK1(cntA, dA.x, pA0 >> 16)     RANK1(cntA, dA.y, pA1 >> 16)
        RANK1(cntA, dA.z, pA2 >> 16)     RANK1(cntA, dA.w, pA3 >> 16)
    }
    __syncthreads();
    if (tid < NB) ALLOC(cntA)
    __syncthreads();
    FLUSH
    __syncthreads();          // slab + pcs reuse guard
    // ---- tile B ----
    if (actB) {
        RANK1(cntB, sB.x, pB0 & 0xFFFFu) RANK1(cntB, sB.y, pB1 & 0xFFFFu)
        RANK1(cntB, sB.z, pB2 & 0xFFFFu) RANK1(cntB, sB.w, pB3 & 0xFFFFu)
        RANK1(cntB, dB.x, pB0 >> 16)     RANK1(cntB, dB.y, pB1 >> 16)
        RANK1(cntB, dB.z, pB2 >> 16)     RANK1(cntB, dB.w, pB3 >> 16)
    }
    __syncthreads();
    if (tid < NB) ALLOC(cntB)
    __syncthreads();
    FLUSH

    #undef RANK1
    #undef ALLOC
    #undef FLUSH
}

__global__ __launch_bounds__(1024) void bucket_accum(
        const unsigned* __restrict__ arena, const unsigned* __restrict__ gcur,
        unsigned* __restrict__ acc) {
    __shared__ unsigned lacc[2][BNODES + 4];     // dual copies; slot 4096 = sink
    unsigned* __restrict__ flat = &lacc[0][0];
    const int tid = threadIdx.x;
    const int b = blockIdx.x >> 1;
    const int half = blockIdx.x & 1;
    for (int k = tid; k < 2 * (BNODES + 4); k += 1024) flat[k] = 0u;
    __syncthreads();
    unsigned* __restrict__ my = lacc[(tid >> 6) & 1];
    unsigned len = gcur[b * 16];                  // padded records, mult of 4
    len = len > (unsigned)CAP ? (unsigned)CAP : len;
    const unsigned h = (len >> 1) & ~3u;
    const unsigned lo4 = (half ? h : 0u) >> 2;
    const unsigned hi4 = (half ? len : h) >> 2;
    const uint4* __restrict__ p =
        reinterpret_cast<const uint4*>(arena + (size_t)b * CAP);
    // paired independent loads per iteration -> both in flight before atomics
    unsigned i = lo4 + tid;
    for (; i + 1024 < hi4; i += 2048) {
        const uint4 v0 = p[i];
        const uint4 v1 = p[i + 1024];
        atomicAdd(&my[v0.x >> 16], (v0.x & 0xFFFFu) | 0x1000000u);
        atomicAdd(&my[v0.y >> 16], (v0.y & 0xFFFFu) | 0x1000000u);
        atomicAdd(&my[v0.z >> 16], (v0.z & 0xFFFFu) | 0x1000000u);
        atomicAdd(&my[v0.w >> 16], (v0.w & 0xFFFFu) | 0x1000000u);
        atomicAdd(&my[v1.x >> 16], (v1.x & 0xFFFFu) | 0x1000000u);
        atomicAdd(&my[v1.y >> 16], (v1.y & 0xFFFFu) | 0x1000000u);
        atomicAdd(&my[v1.z >> 16], (v1.z & 0xFFFFu) | 0x1000000u);
        atomicAdd(&my[v1.w >> 16], (v1.w & 0xFFFFu) | 0x1000000u);
    }
    if (i < hi4) {
        const uint4 v = p[i];
        atomicAdd(&my[v.x >> 16], (v.x & 0xFFFFu) | 0x1000000u);
        atomicAdd(&my[v.y >> 16], (v.y & 0xFFFFu) | 0x1000000u);
        atomicAdd(&my[v.z >> 16], (v.z & 0xFFFFu) | 0x1000000u);
        atomicAdd(&my[v.w >> 16], (v.w & 0xFFFFu) | 0x1000000u);
    }
    __syncthreads();
    const int base = b << BSHIFT;
    unsigned* __restrict__ dst = acc + (size_t)half * kNodes;
    for (int k = tid; k < BNODES; k += 1024) {
        const int nn = base + k;
        if (nn < kNodes) dst[nn] = lacc[0][k] + lacc[1][k];
    }
}

// Exact fixup for the (statistically ~0.02 expected) slab-overflow records.
__global__ __launch_bounds__(256) void ovf_fix(
        const unsigned long long* __restrict__ ovf,
        const unsigned* __restrict__ gcur, unsigned* __restrict__ acc) {
    unsigned n = gcur[NB * 16];
    n = n > OVFCAP ? OVFCAP : n;
    for (unsigned i = threadIdx.x; i < n; i += 256) {
        const unsigned long long v = ovf[i];
        atomicAdd(&acc[(unsigned)(v >> 16)],
                  ((unsigned)v & 0xFFFFu) | 0x1000000u);
    }
}

// ---------------- Fallback (atomic u64) path ----------------
constexpr float kScale = 1048576.0f;           // 2^20
constexpr float kInvScale = 1.0f / 1048576.0f;
constexpr long long kBias = 1ll << 36;

__global__ __launch_bounds__(256) void zero_acc(unsigned long long* __restrict__ acc) {
    int i = blockIdx.x * 256 + threadIdx.x;
    if (i < kNodes) acc[i] = 0ull;
}

__global__ __launch_bounds__(256) void edge_kernel(
        const int* __restrict__ ei,
        const float* __restrict__ orc,
        unsigned long long* __restrict__ acc) {
    int t = blockIdx.x * 256 + threadIdx.x;
    int e0 = t * 4;
    if (e0 >= kEdges) return;
    const int4 s4 = *reinterpret_cast<const int4*>(ei + e0);
    const int4 d4 = *reinterpret_cast<const int4*>(ei + kEdges + e0);
    const int ss[4] = {s4.x, s4.y, s4.z, s4.w};
    const int dd[4] = {d4.x, d4.y, d4.z, d4.w};
    #pragma unroll
    for (int k = 0; k < 4; ++k) {
        const float os = orc[ss[k]];
        const float od = orc[dd[k]];
        const unsigned long long ps =
            (1ull << 48) + (unsigned long long)(kBias + (long long)__float2ll_rn(od * kScale));
        const unsigned long long pd =
            (1ull << 48) + (unsigned long long)(kBias + (long long)__float2ll_rn(os * kScale));
        atomicAdd(&acc[ss[k]], ps);
        atomicAdd(&acc[dd[k]], pd);
    }
}

// ---------------- Node phase ----------------
// MODE 0: u64 cell, deg<<48 | biased 2^20 fixed sum.
// MODE 3: two u32 partials, each deg<<24 | sum(q16).
template <int MODE>
__global__ __launch_bounds__(256) void node_kernel(
        const float* __restrict__ orc,
        const unsigned long long* __restrict__ acc64,
        const unsigned* __restrict__ acc32,
        const float* __restrict__ W1, const float* __restrict__ b1,
        const float* __restrict__ W2, const float* __restrict__ b2,
        const float* __restrict__ gamma, const float* __restrict__ beta,
        float* __restrict__ out) {
    const int i = blockIdx.x * 256 + threadIdx.x;
    if (i >= kNodes) return;

    const float x0 = orc[i];
    float nb;
    if (MODE == 0) {
        const unsigned long long p = acc64[i];
        const unsigned deg = (unsigned)(p >> 48);
        const long long sf = (long long)(p & ((1ull << 48) - 1)) - (long long)deg * kBias;
        const float s = (float)sf * kInvScale;
        nb = (deg > 0) ? s / (float)deg : 0.0f;
    } else {
        const unsigned p0 = acc32[i];
        const unsigned p1 = acc32[kNodes + i];
        const unsigned deg = (p0 >> 24) + (p1 >> 24);
        const unsigned sumq = (p0 & 0xFFFFFFu) + (p1 & 0xFFFFFFu);
        nb = (deg > 0)
            ? ((float)sumq * (1.0f / 32768.0f) / (float)deg - 1.0f) : 0.0f;
    }

    constexpr float kPi = 3.14159265358979323846f;
    float Phi[16];
    const float n0 = __saturatef((x0 + 1.0f) * 0.5f);
    const float n1 = __saturatef((nb + 1.0f) * 0.5f);
    #pragma unroll
    for (int k = 0; k < 4; ++k) {
        const float a0 = n0 * (float)(k + 1) * kPi;
        const float a1 = n1 * (float)(k + 1) * kPi;
        Phi[2 * k]     = __sinf(a0);
        Phi[2 * k + 1] = __cosf(a0);
        Phi[8 + 2 * k]     = __sinf(a1);
        Phi[8 + 2 * k + 1] = __cosf(a1);
    }

    float y[16];
    #pragma unroll
    for (int d = 0; d < 16; ++d) y[d] = b2[d];
    #pragma unroll
    for (int j = 0; j < 32; ++j) {
        float a = b1[j];
        #pragma unroll
        for (int d = 0; d < 16; ++d) a = fmaf(Phi[d], W1[j * 16 + d], a);
        a = fmaxf(a, 0.0f);
        #pragma unroll
        for (int d = 0; d < 16; ++d) y[d] = fmaf(a, W2[d * 32 + j], y[d]);
    }

    float mu = 0.0f;
    #pragma unroll
    for (int d = 0; d < 16; ++d) mu += y[d];
    mu *= (1.0f / 16.0f);
    float var = 0.0f;
    #pragma unroll
    for (int d = 0; d < 16; ++d) { const float t = y[d] - mu; var = fmaf(t, t, var); }
    var *= (1.0f / 16.0f);
    const float inv = rsqrtf(var + 1e-5f);

    float4* o4 = reinterpret_cast<float4*>(out + (size_t)i * 16);
    #pragma unroll
    for (int q = 0; q < 4; ++q) {
        float4 o;
        o.x = (y[4 * q + 0] - mu) * inv * gamma[4 * q + 0] + beta[4 * q + 0] + Phi[4 * q + 0];
        o.y = (y[4 * q + 1] - mu) * inv * gamma[4 * q + 1] + beta[4 * q + 1] + Phi[4 * q + 1];
        o.z = (y[4 * q + 2] - mu) * inv * gamma[4 * q + 2] + beta[4 * q + 2] + Phi[4 * q + 2];
        o.w = (y[4 * q + 3] - mu) * inv * gamma[4 * q + 3] + beta[4 * q + 3] + Phi[4 * q + 3];
        o4[q] = o;
    }
}

extern "C" void kernel_launch(void* const* d_in, const int* in_sizes, int n_in,
                              void* d_out, int out_size, void* d_ws, size_t ws_size,
                              hipStream_t stream) {
    const float* orc   = (const float*)d_in[0];
    const int*   ei    = (const int*)d_in[1];
    const float* W1    = (const float*)d_in[2];
    const float* b1    = (const float*)d_in[3];
    const float* W2    = (const float*)d_in[4];
    const float* b2    = (const float*)d_in[5];
    const float* gamma = (const float*)d_in[6];
    const float* beta  = (const float*)d_in[7];
    float* out = (float*)d_out;
    char* ws = (char*)d_ws;

    if (ws_size >= kWsNeeded) {
        unsigned* arena = (unsigned*)ws;
        unsigned* gcur = (unsigned*)(ws + kCurOff);
        unsigned* acc = (unsigned*)(ws + kAccOff);
        unsigned short* orcq = (unsigned short*)(ws + kOrcqOff);
        unsigned long long* ovf = (unsigned long long*)(ws + kOvfOff);
        quant_orc<<<(kNodes / 4 + 255) / 256, 256, 0, stream>>>(orc, orcq, gcur);
        scatter_sort<<<(TILES + 1) / 2, 1024, 0, stream>>>(ei, orcq, arena, gcur, ovf);
        bucket_accum<<<NBUSED * SPLIT, 1024, 0, stream>>>(arena, gcur, acc);
        ovf_fix<<<1, 256, 0, stream>>>(ovf, gcur, acc);
        node_kernel<3><<<(kNodes + 255) / 256, 256, 0, stream>>>(
            orc, nullptr, acc, W1, b1, W2, b2, gamma, beta, out);
    } else {
        unsigned long long* acc = (unsigned long long*)ws;  // 8 MB
        zero_acc<<<(kNodes + 255) / 256, 256, 0, stream>>>(acc);
        edge_kernel<<<(kEdges / 4 + 255) / 256, 256, 0, stream>>>(ei, orc, acc);
        node_kernel<0><<<(kNodes + 255) / 256, 256, 0, stream>>>(
            orc, acc, nullptr, W1, b1, W2, b2, gamma, beta, out);
    }
}